// Round 13
// baseline (37.140 us; speedup 1.0000x reference)
//
#include <hip/hip_runtime.h>

// Chamfer distance via MFMA (bf16 split-precision, exact products), fp32 in/out.
// B=4, N=M=8192.  d_ij = |p|^2 + |t|^2 - 2 p.t.
// A-row (target, prep-formatted): [-2th(xyz) -2tl(xyz) -2th(xyz) -2tl(xyz) t2h t2l 0 0]
// B-row (pred, built in-wave):    [ ph(xyz)   ph(xyz)   pl(xyz)   pl(xyz)  1   1  0 0]
// One mfma_f32_32x32x16_bf16 -> 32x32 of (d_ij - |p_j|^2); exact (absmax 0.0, r9-r12).
// v4: latency-oriented mfma kernel: R=2 col-blocks (32 acc VGPR), dedicated zero-C
// tuple, depth-2 prefetch, ~6 waves/SIMD TLP (8192 waves).

typedef short s8v __attribute__((ext_vector_type(8)));
typedef float f16v __attribute__((ext_vector_type(16)));

#define NPTS 8192
#define NB 4
#define CHUNKS 8          // target chunks of 1024 (32 tiles of 32)

__device__ inline unsigned short f2bf(float f) {          // fp32 -> bf16 (RNE)
    unsigned u = __builtin_bit_cast(unsigned, f);
    unsigned r = u + 0x7FFFu + ((u >> 16) & 1u);
    return (unsigned short)(r >> 16);
}
__device__ inline float bf2f(unsigned short s) {
    unsigned u = ((unsigned)s) << 16;
    return __builtin_bit_cast(float, u);
}
__device__ inline s8v load16(const unsigned short* p) {   // 8 bf16 = 16 B
    int4 v = *(const int4*)p;
    return __builtin_bit_cast(s8v, v);
}
// fold 16 acc values + running min (v_min3 chain)
__device__ inline float mintree(const f16v& c, float mn) {
    float m = fminf(fminf(c[0], c[1]), c[2]);
    m = fminf(fminf(m, c[3]), c[4]);
    m = fminf(fminf(m, c[5]), c[6]);
    m = fminf(fminf(m, c[7]), c[8]);
    m = fminf(fminf(m, c[9]), c[10]);
    m = fminf(fminf(m, c[11]), c[12]);
    m = fminf(fminf(m, c[13]), c[14]);
    return fminf(fminf(m, c[15]), mn);
}

// ---- K1 prep: format both clouds as A-rows; zero the ticket ----
__global__ __launch_bounds__(256) void chamfer_prep(
    const float* __restrict__ pred, const float* __restrict__ target,
    unsigned short* __restrict__ afmt, int* __restrict__ done)
{
    if (blockIdx.x == 0 && threadIdx.x == 0) *done = 0;

    const int g = blockIdx.x * 256 + threadIdx.x;   // 0..65535
    const int c = g >> 15;
    const int rem = g & 32767;                      // b*NPTS + i
    const float* src = (c == 0 ? pred : target) + (size_t)rem * 3;
    const float x = src[0], y = src[1], z = src[2];

    const unsigned short hx = f2bf(x), hy = f2bf(y), hz = f2bf(z);
    const float fx = bf2f(hx), fy = bf2f(hy), fz = bf2f(hz);
    const unsigned short lx = f2bf(x - fx), ly = f2bf(y - fy), lz = f2bf(z - fz);
    const float t2 = x*x + y*y + z*z;
    const unsigned short t2h = f2bf(t2);
    const unsigned short t2l = f2bf(t2 - bf2f(t2h));

    union { unsigned short u[16]; int4 v[2]; } A;
    A.u[0] = f2bf(-2.f*fx); A.u[1] = f2bf(-2.f*fy); A.u[2] = f2bf(-2.f*fz);
    A.u[3] = f2bf(-2.f*bf2f(lx)); A.u[4] = f2bf(-2.f*bf2f(ly)); A.u[5] = f2bf(-2.f*bf2f(lz));
    A.u[6] = A.u[0]; A.u[7] = A.u[1]; A.u[8] = A.u[2];
    A.u[9] = A.u[3]; A.u[10] = A.u[4]; A.u[11] = A.u[5];
    A.u[12] = t2h; A.u[13] = t2l; A.u[14] = 0; A.u[15] = 0;

    // slot (1-c): dir0 (pred->target) uses A=target (c=1 -> slot 0)
    int4* ap = (int4*)(afmt + ((size_t)(1 - c) * 32768 + rem) * 16);
    ap[0] = A.v[0]; ap[1] = A.v[1];
}

// ---- K2 main: wave owns 64 preds (2 col-blocks), streams 1 chunk (32 tiles) ----
__global__ __launch_bounds__(256, 6) void chamfer_mfma(
    const float* __restrict__ pred, const float* __restrict__ target,
    const unsigned short* __restrict__ afmt,
    float* __restrict__ pmins)
{
    const int dirb = blockIdx.y;            // dir*4 + b
    const int dir  = dirb >> 2;
    const int b    = dirb & 3;
    const int chunk = blockIdx.z;
    const int wid  = threadIdx.x >> 6;
    const int lane = threadIdx.x & 63;
    const int half = lane >> 5;
    const int l31  = lane & 31;
    const int w    = blockIdx.x * 4 + wid;  // 0..127
    const int base = w * 64;                // first pred of this wave

    // build 2 B-frags in-register from raw coords (layout validated r9)
    const float* pc = ((dir == 0) ? pred : target) + (size_t)b * NPTS * 3;
    s8v bf0, bf1;
#pragma unroll
    for (int q = 0; q < 2; ++q) {
        const float* sp = pc + (size_t)(base + q * 32 + l31) * 3;
        const float x = sp[0], y = sp[1], z = sp[2];
        const unsigned short hx = f2bf(x), hy = f2bf(y), hz = f2bf(z);
        const unsigned short lx = f2bf(x - bf2f(hx));
        const unsigned short ly = f2bf(y - bf2f(hy));
        const unsigned short lz = f2bf(z - bf2f(hz));
        union { unsigned short u[8]; s8v v; } F;
        if (half == 0) {
            F.u[0] = hx; F.u[1] = hy; F.u[2] = hz;
            F.u[3] = hx; F.u[4] = hy; F.u[5] = hz;
            F.u[6] = lx; F.u[7] = ly;
        } else {
            F.u[0] = lz; F.u[1] = lx; F.u[2] = ly; F.u[3] = lz;
            F.u[4] = 0x3F80; F.u[5] = 0x3F80; F.u[6] = 0; F.u[7] = 0;
        }
        if (q == 0) bf0 = F.v; else bf1 = F.v;
    }

    // stream this chunk's 32 A-tiles (512 ushorts each)
    const size_t cbase = ((size_t)dir * NB + b) * NPTS;
    const unsigned short* aptr = afmt + cbase * 16
        + (size_t)chunk * 32 * 512 + (l31 * 16 + half * 8);

    f16v zf = {};                           // dedicated zero-C tuple (16 VGPR)
    float mn0 = 1e30f, mn1 = 1e30f;

    s8v Aa = load16(aptr + 0*512);
    s8v Ab = load16(aptr + 1*512);

#pragma unroll
    for (int t = 0; t < 32; t += 2) {
        {
            f16v c0 = __builtin_amdgcn_mfma_f32_32x32x16_bf16(Aa, bf0, zf, 0,0,0);
            f16v c1 = __builtin_amdgcn_mfma_f32_32x32x16_bf16(Aa, bf1, zf, 0,0,0);
            Aa = load16(aptr + (((t + 2) & 31) * 512));
            mn0 = mintree(c0, mn0);
            mn1 = mintree(c1, mn1);
        }
        {
            f16v c0 = __builtin_amdgcn_mfma_f32_32x32x16_bf16(Ab, bf0, zf, 0,0,0);
            f16v c1 = __builtin_amdgcn_mfma_f32_32x32x16_bf16(Ab, bf1, zf, 0,0,0);
            Ab = load16(aptr + (((t + 3) & 31) * 512));
            mn0 = mintree(c0, mn0);
            mn1 = mintree(c1, mn1);
        }
    }

    // merge row-halves: lane^32 holds the other 16 target-rows
    mn0 = fminf(mn0, __shfl_xor(mn0, 32));
    mn1 = fminf(mn1, __shfl_xor(mn1, 32));

    if (half == 0) {
        float* dst = pmins + ((size_t)dirb * CHUNKS + chunk) * NPTS + base + l31;
        dst[0]  = mn0;
        dst[32] = mn1;
    }
}

// ---- K3: merge chunks + |p|^2 + block partial sums + last-block final reduce ----
__global__ __launch_bounds__(256) void chamfer_mergefin(
    const float* __restrict__ pred, const float* __restrict__ target,
    const float* __restrict__ pmins, float* __restrict__ partials,
    int* __restrict__ done, float* __restrict__ out)
{
    const int tid = threadIdx.x;
    const int t = blockIdx.x * 256 + tid;           // 0..65535
    const int dirb = t >> 13;
    const int pr   = t & 8191;
    const int dir  = dirb >> 2;
    const int b    = dirb & 3;

    const float* mrow = pmins + (size_t)dirb * CHUNKS * NPTS + pr;
    float m = fminf(fminf(mrow[0*NPTS], mrow[1*NPTS]), mrow[2*NPTS]);
    m = fminf(fminf(m, mrow[3*NPTS]), mrow[4*NPTS]);
    m = fminf(fminf(m, mrow[5*NPTS]), mrow[6*NPTS]);
    m = fminf(m, mrow[7*NPTS]);

    const float* sp = ((dir == 0) ? pred : target) + ((size_t)b * NPTS + pr) * 3;
    const float p2 = sp[0]*sp[0] + sp[1]*sp[1] + sp[2]*sp[2];
    float v = (m + p2) * (1.0f / 32768.0f);

    __shared__ float s[256];
    __shared__ int lastFlag;
    s[tid] = v;
    __syncthreads();
    for (int wd = 128; wd > 0; wd >>= 1) {
        if (tid < wd) s[tid] += s[tid + wd];
        __syncthreads();
    }
    if (tid == 0) {
        __hip_atomic_store(&partials[blockIdx.x], s[0],
                           __ATOMIC_RELEASE, __HIP_MEMORY_SCOPE_AGENT);
        int prev = __hip_atomic_fetch_add(done, 1,
                           __ATOMIC_ACQ_REL, __HIP_MEMORY_SCOPE_AGENT);
        lastFlag = (prev == gridDim.x - 1);
    }
    __syncthreads();

    if (lastFlag) {   // exactly one block; fixed-order sum -> deterministic
        float acc = __hip_atomic_load(&partials[tid],
                           __ATOMIC_ACQUIRE, __HIP_MEMORY_SCOPE_AGENT);
        s[tid] = acc;
        __syncthreads();
        for (int wd = 128; wd > 0; wd >>= 1) {
            if (tid < wd) s[tid] += s[tid + wd];
            __syncthreads();
        }
        if (tid == 0) out[0] = s[0];
    }
}

extern "C" void kernel_launch(void* const* d_in, const int* in_sizes, int n_in,
                              void* d_out, int out_size, void* d_ws, size_t ws_size,
                              hipStream_t stream)
{
    const float* pred   = (const float*)d_in[0];
    const float* target = (const float*)d_in[1];
    float* out = (float*)d_out;

    // ws: afmt 2 MB | pmins 2 MB | partials 1 KB | done counter
    unsigned short* afmt = (unsigned short*)d_ws;
    float* pmins    = (float*)((char*)d_ws + (size_t)2 * 1024 * 1024);
    float* partials = (float*)((char*)d_ws + (size_t)4 * 1024 * 1024);
    int*   done     = (int*)((char*)d_ws + (size_t)5 * 1024 * 1024);

    chamfer_prep<<<256, 256, 0, stream>>>(pred, target, afmt, done);

    dim3 grid(32, 8, CHUNKS);   // 2048 blocks x 4 waves = 8192 waves (~6-8/SIMD)
    chamfer_mfma<<<grid, 256, 0, stream>>>(pred, target, afmt, pmins);

    chamfer_mergefin<<<256, 256, 0, stream>>>(pred, target, pmins, partials, done, out);
}

// Round 14
// 37.123 us; speedup vs baseline: 1.0005x; 1.0005x over previous
//
#include <hip/hip_runtime.h>

// Chamfer distance via MFMA (bf16 split-precision, exact products), fp32 in/out.
// B=4, N=M=8192.  d_ij = |p|^2 + |t|^2 - 2 p.t.
// A-row (target, prep-formatted): [-2th(xyz) -2tl(xyz) -2th(xyz) -2tl(xyz) t2h t2l 0 0]
// B-row (pred, built in-wave):    [ ph(xyz)   ph(xyz)   pl(xyz)   pl(xyz)  1   1  0 0]
// One mfma_f32_32x32x16_bf16 -> 32x32 of (d_ij - |p_j|^2); exact (absmax 0.0, r9-r13).
// v5: v4 with launch_bounds(256,4) (128 VGPR cap) -- room for MFMA results in
// VGPRs (unified file) so the mintree reads them without accvgpr moves.

typedef short s8v __attribute__((ext_vector_type(8)));
typedef float f16v __attribute__((ext_vector_type(16)));

#define NPTS 8192
#define NB 4
#define CHUNKS 8          // target chunks of 1024 (32 tiles of 32)

__device__ inline unsigned short f2bf(float f) {          // fp32 -> bf16 (RNE)
    unsigned u = __builtin_bit_cast(unsigned, f);
    unsigned r = u + 0x7FFFu + ((u >> 16) & 1u);
    return (unsigned short)(r >> 16);
}
__device__ inline float bf2f(unsigned short s) {
    unsigned u = ((unsigned)s) << 16;
    return __builtin_bit_cast(float, u);
}
__device__ inline s8v load16(const unsigned short* p) {   // 8 bf16 = 16 B
    int4 v = *(const int4*)p;
    return __builtin_bit_cast(s8v, v);
}
// fold 16 acc values + running min (v_min3 chain)
__device__ inline float mintree(const f16v& c, float mn) {
    float m = fminf(fminf(c[0], c[1]), c[2]);
    m = fminf(fminf(m, c[3]), c[4]);
    m = fminf(fminf(m, c[5]), c[6]);
    m = fminf(fminf(m, c[7]), c[8]);
    m = fminf(fminf(m, c[9]), c[10]);
    m = fminf(fminf(m, c[11]), c[12]);
    m = fminf(fminf(m, c[13]), c[14]);
    return fminf(fminf(m, c[15]), mn);
}

// ---- K1 prep: format both clouds as A-rows; zero the ticket ----
__global__ __launch_bounds__(256) void chamfer_prep(
    const float* __restrict__ pred, const float* __restrict__ target,
    unsigned short* __restrict__ afmt, int* __restrict__ done)
{
    if (blockIdx.x == 0 && threadIdx.x == 0) *done = 0;

    const int g = blockIdx.x * 256 + threadIdx.x;   // 0..65535
    const int c = g >> 15;
    const int rem = g & 32767;                      // b*NPTS + i
    const float* src = (c == 0 ? pred : target) + (size_t)rem * 3;
    const float x = src[0], y = src[1], z = src[2];

    const unsigned short hx = f2bf(x), hy = f2bf(y), hz = f2bf(z);
    const float fx = bf2f(hx), fy = bf2f(hy), fz = bf2f(hz);
    const unsigned short lx = f2bf(x - fx), ly = f2bf(y - fy), lz = f2bf(z - fz);
    const float t2 = x*x + y*y + z*z;
    const unsigned short t2h = f2bf(t2);
    const unsigned short t2l = f2bf(t2 - bf2f(t2h));

    union { unsigned short u[16]; int4 v[2]; } A;
    A.u[0] = f2bf(-2.f*fx); A.u[1] = f2bf(-2.f*fy); A.u[2] = f2bf(-2.f*fz);
    A.u[3] = f2bf(-2.f*bf2f(lx)); A.u[4] = f2bf(-2.f*bf2f(ly)); A.u[5] = f2bf(-2.f*bf2f(lz));
    A.u[6] = A.u[0]; A.u[7] = A.u[1]; A.u[8] = A.u[2];
    A.u[9] = A.u[3]; A.u[10] = A.u[4]; A.u[11] = A.u[5];
    A.u[12] = t2h; A.u[13] = t2l; A.u[14] = 0; A.u[15] = 0;

    // slot (1-c): dir0 (pred->target) uses A=target (c=1 -> slot 0)
    int4* ap = (int4*)(afmt + ((size_t)(1 - c) * 32768 + rem) * 16);
    ap[0] = A.v[0]; ap[1] = A.v[1];
}

// ---- K2 main: wave owns 64 preds (2 col-blocks), streams 1 chunk (32 tiles) ----
__global__ __launch_bounds__(256, 4) void chamfer_mfma(
    const float* __restrict__ pred, const float* __restrict__ target,
    const unsigned short* __restrict__ afmt,
    float* __restrict__ pmins)
{
    const int dirb = blockIdx.y;            // dir*4 + b
    const int dir  = dirb >> 2;
    const int b    = dirb & 3;
    const int chunk = blockIdx.z;
    const int wid  = threadIdx.x >> 6;
    const int lane = threadIdx.x & 63;
    const int half = lane >> 5;
    const int l31  = lane & 31;
    const int w    = blockIdx.x * 4 + wid;  // 0..127
    const int base = w * 64;                // first pred of this wave

    // build 2 B-frags in-register from raw coords (layout validated r9)
    const float* pc = ((dir == 0) ? pred : target) + (size_t)b * NPTS * 3;
    s8v bf0, bf1;
#pragma unroll
    for (int q = 0; q < 2; ++q) {
        const float* sp = pc + (size_t)(base + q * 32 + l31) * 3;
        const float x = sp[0], y = sp[1], z = sp[2];
        const unsigned short hx = f2bf(x), hy = f2bf(y), hz = f2bf(z);
        const unsigned short lx = f2bf(x - bf2f(hx));
        const unsigned short ly = f2bf(y - bf2f(hy));
        const unsigned short lz = f2bf(z - bf2f(hz));
        union { unsigned short u[8]; s8v v; } F;
        if (half == 0) {
            F.u[0] = hx; F.u[1] = hy; F.u[2] = hz;
            F.u[3] = hx; F.u[4] = hy; F.u[5] = hz;
            F.u[6] = lx; F.u[7] = ly;
        } else {
            F.u[0] = lz; F.u[1] = lx; F.u[2] = ly; F.u[3] = lz;
            F.u[4] = 0x3F80; F.u[5] = 0x3F80; F.u[6] = 0; F.u[7] = 0;
        }
        if (q == 0) bf0 = F.v; else bf1 = F.v;
    }

    // stream this chunk's 32 A-tiles (512 ushorts each)
    const size_t cbase = ((size_t)dir * NB + b) * NPTS;
    const unsigned short* aptr = afmt + cbase * 16
        + (size_t)chunk * 32 * 512 + (l31 * 16 + half * 8);

    f16v zf = {};                           // zero-C tuple
    float mn0 = 1e30f, mn1 = 1e30f;

    s8v Aa = load16(aptr + 0*512);
    s8v Ab = load16(aptr + 1*512);

#pragma unroll
    for (int t = 0; t < 32; t += 2) {
        {
            f16v c0 = __builtin_amdgcn_mfma_f32_32x32x16_bf16(Aa, bf0, zf, 0,0,0);
            f16v c1 = __builtin_amdgcn_mfma_f32_32x32x16_bf16(Aa, bf1, zf, 0,0,0);
            Aa = load16(aptr + (((t + 2) & 31) * 512));
            mn0 = mintree(c0, mn0);
            mn1 = mintree(c1, mn1);
        }
        {
            f16v c0 = __builtin_amdgcn_mfma_f32_32x32x16_bf16(Ab, bf0, zf, 0,0,0);
            f16v c1 = __builtin_amdgcn_mfma_f32_32x32x16_bf16(Ab, bf1, zf, 0,0,0);
            Ab = load16(aptr + (((t + 3) & 31) * 512));
            mn0 = mintree(c0, mn0);
            mn1 = mintree(c1, mn1);
        }
    }

    // merge row-halves: lane^32 holds the other 16 target-rows
    mn0 = fminf(mn0, __shfl_xor(mn0, 32));
    mn1 = fminf(mn1, __shfl_xor(mn1, 32));

    if (half == 0) {
        float* dst = pmins + ((size_t)dirb * CHUNKS + chunk) * NPTS + base + l31;
        dst[0]  = mn0;
        dst[32] = mn1;
    }
}

// ---- K3: merge chunks + |p|^2 + block partial sums + last-block final reduce ----
__global__ __launch_bounds__(256) void chamfer_mergefin(
    const float* __restrict__ pred, const float* __restrict__ target,
    const float* __restrict__ pmins, float* __restrict__ partials,
    int* __restrict__ done, float* __restrict__ out)
{
    const int tid = threadIdx.x;
    const int t = blockIdx.x * 256 + tid;           // 0..65535
    const int dirb = t >> 13;
    const int pr   = t & 8191;
    const int dir  = dirb >> 2;
    const int b    = dirb & 3;

    const float* mrow = pmins + (size_t)dirb * CHUNKS * NPTS + pr;
    float m = fminf(fminf(mrow[0*NPTS], mrow[1*NPTS]), mrow[2*NPTS]);
    m = fminf(fminf(m, mrow[3*NPTS]), mrow[4*NPTS]);
    m = fminf(fminf(m, mrow[5*NPTS]), mrow[6*NPTS]);
    m = fminf(m, mrow[7*NPTS]);

    const float* sp = ((dir == 0) ? pred : target) + ((size_t)b * NPTS + pr) * 3;
    const float p2 = sp[0]*sp[0] + sp[1]*sp[1] + sp[2]*sp[2];
    float v = (m + p2) * (1.0f / 32768.0f);

    __shared__ float s[256];
    __shared__ int lastFlag;
    s[tid] = v;
    __syncthreads();
    for (int wd = 128; wd > 0; wd >>= 1) {
        if (tid < wd) s[tid] += s[tid + wd];
        __syncthreads();
    }
    if (tid == 0) {
        __hip_atomic_store(&partials[blockIdx.x], s[0],
                           __ATOMIC_RELEASE, __HIP_MEMORY_SCOPE_AGENT);
        int prev = __hip_atomic_fetch_add(done, 1,
                           __ATOMIC_ACQ_REL, __HIP_MEMORY_SCOPE_AGENT);
        lastFlag = (prev == gridDim.x - 1);
    }
    __syncthreads();

    if (lastFlag) {   // exactly one block; fixed-order sum -> deterministic
        float acc = __hip_atomic_load(&partials[tid],
                           __ATOMIC_ACQUIRE, __HIP_MEMORY_SCOPE_AGENT);
        s[tid] = acc;
        __syncthreads();
        for (int wd = 128; wd > 0; wd >>= 1) {
            if (tid < wd) s[tid] += s[tid + wd];
            __syncthreads();
        }
        if (tid == 0) out[0] = s[0];
    }
}

extern "C" void kernel_launch(void* const* d_in, const int* in_sizes, int n_in,
                              void* d_out, int out_size, void* d_ws, size_t ws_size,
                              hipStream_t stream)
{
    const float* pred   = (const float*)d_in[0];
    const float* target = (const float*)d_in[1];
    float* out = (float*)d_out;

    // ws: afmt 2 MB | pmins 2 MB | partials 1 KB | done counter
    unsigned short* afmt = (unsigned short*)d_ws;
    float* pmins    = (float*)((char*)d_ws + (size_t)2 * 1024 * 1024);
    float* partials = (float*)((char*)d_ws + (size_t)4 * 1024 * 1024);
    int*   done     = (int*)((char*)d_ws + (size_t)5 * 1024 * 1024);

    chamfer_prep<<<256, 256, 0, stream>>>(pred, target, afmt, done);

    dim3 grid(32, 8, CHUNKS);   // 2048 blocks x 4 waves = 8192 waves
    chamfer_mfma<<<grid, 256, 0, stream>>>(pred, target, afmt, pmins);

    chamfer_mergefin<<<256, 256, 0, stream>>>(pred, target, pmins, partials, done, out);
}

// Round 16
// 36.424 us; speedup vs baseline: 1.0197x; 1.0192x over previous
//
#include <hip/hip_runtime.h>

// Chamfer distance via MFMA (bf16 split-precision, exact products), fp32 in/out.
// B=4, N=M=8192.  d_ij = |p|^2 + |t|^2 - 2 p.t.
// A-row (target, prep-formatted): [-2th(xyz) -2tl(xyz) -2th(xyz) -2tl(xyz) t2h t2l 0 0]
// B-row (pred, built in-wave):    [ ph(xyz)   ph(xyz)   pl(xyz)   pl(xyz)  1   1  0 0]
// One mfma_f32_32x32x16_bf16 -> 32x32 of (d_ij - |p_j|^2); exact (absmax 0.0, r9-r14).
// v6: v2 geometry (R=4, 1024 blocks, 4 waves) + LDS-staged A-stream:
// block stages 32KB chunk in 4 x 8KB double-buffered stages (loads issued a full
// compute-phase early), waves consume via ds_read_b128; parallel depth-3 mintree.

typedef short s8v __attribute__((ext_vector_type(8)));
typedef float f16v __attribute__((ext_vector_type(16)));

#define NPTS 8192
#define NB 4
#define CHUNKS 8          // target chunks of 1024 (32 tiles of 32)

__device__ inline unsigned short f2bf(float f) {          // fp32 -> bf16 (RNE)
    unsigned u = __builtin_bit_cast(unsigned, f);
    unsigned r = u + 0x7FFFu + ((u >> 16) & 1u);
    return (unsigned short)(r >> 16);
}
__device__ inline float bf2f(unsigned short s) {
    unsigned u = ((unsigned)s) << 16;
    return __builtin_bit_cast(float, u);
}
__device__ inline s8v i2s(int4 v) { return __builtin_bit_cast(s8v, v); }

// fold 16 acc values + running min; parallel (depth 3), min3-shaped
__device__ inline float mintree(const f16v& c, float mn) {
    float m0 = fminf(fminf(c[0],  c[1]),  c[2]);
    float m1 = fminf(fminf(c[3],  c[4]),  c[5]);
    float m2 = fminf(fminf(c[6],  c[7]),  c[8]);
    float m3 = fminf(fminf(c[9],  c[10]), c[11]);
    float m4 = fminf(fminf(c[12], c[13]), c[14]);
    float m5 = fminf(fminf(m0, m1), m2);
    float m6 = fminf(fminf(m3, m4), c[15]);
    return fminf(fminf(m5, m6), mn);
}

// ---- K1 prep: format both clouds as A-rows; zero the ticket ----
__global__ __launch_bounds__(256) void chamfer_prep(
    const float* __restrict__ pred, const float* __restrict__ target,
    unsigned short* __restrict__ afmt, int* __restrict__ done)
{
    if (blockIdx.x == 0 && threadIdx.x == 0) *done = 0;

    const int g = blockIdx.x * 256 + threadIdx.x;   // 0..65535
    const int c = g >> 15;
    const int rem = g & 32767;                      // b*NPTS + i
    const float* src = (c == 0 ? pred : target) + (size_t)rem * 3;
    const float x = src[0], y = src[1], z = src[2];

    const unsigned short hx = f2bf(x), hy = f2bf(y), hz = f2bf(z);
    const float fx = bf2f(hx), fy = bf2f(hy), fz = bf2f(hz);
    const unsigned short lx = f2bf(x - fx), ly = f2bf(y - fy), lz = f2bf(z - fz);
    const float t2 = x*x + y*y + z*z;
    const unsigned short t2h = f2bf(t2);
    const unsigned short t2l = f2bf(t2 - bf2f(t2h));

    union { unsigned short u[16]; int4 v[2]; } A;
    A.u[0] = f2bf(-2.f*fx); A.u[1] = f2bf(-2.f*fy); A.u[2] = f2bf(-2.f*fz);
    A.u[3] = f2bf(-2.f*bf2f(lx)); A.u[4] = f2bf(-2.f*bf2f(ly)); A.u[5] = f2bf(-2.f*bf2f(lz));
    A.u[6] = A.u[0]; A.u[7] = A.u[1]; A.u[8] = A.u[2];
    A.u[9] = A.u[3]; A.u[10] = A.u[4]; A.u[11] = A.u[5];
    A.u[12] = t2h; A.u[13] = t2l; A.u[14] = 0; A.u[15] = 0;

    // slot (1-c): dir0 (pred->target) uses A=target (c=1 -> slot 0)
    int4* ap = (int4*)(afmt + ((size_t)(1 - c) * 32768 + rem) * 16);
    ap[0] = A.v[0]; ap[1] = A.v[1];
}

// ---- K2 main: block owns 512 preds (4 waves x R=4), LDS-stages 1 chunk ----
__global__ __launch_bounds__(256, 4) void chamfer_mfma(
    const float* __restrict__ pred, const float* __restrict__ target,
    const unsigned short* __restrict__ afmt,
    float* __restrict__ pmins)
{
    __shared__ int4 sbuf[2][512];           // 2 x 8KB double buffer

    const int dirb = blockIdx.y;            // dir*4 + b
    const int dir  = dirb >> 2;
    const int b    = dirb & 3;
    const int chunk = blockIdx.z;
    const int tid  = threadIdx.x;
    const int wid  = tid >> 6;
    const int lane = tid & 63;
    const int half = lane >> 5;
    const int l31  = lane & 31;
    const int w    = blockIdx.x * 4 + wid;  // 0..63
    const int base = w * 128;               // first pred of this wave

    // build 4 B-frags in-register from raw coords (layout validated r9/r10)
    const float* pc = ((dir == 0) ? pred : target) + (size_t)b * NPTS * 3;
    s8v bfrag[4];
#pragma unroll
    for (int q = 0; q < 4; ++q) {
        const float* sp = pc + (size_t)(base + q * 32 + l31) * 3;
        const float x = sp[0], y = sp[1], z = sp[2];
        const unsigned short hx = f2bf(x), hy = f2bf(y), hz = f2bf(z);
        const unsigned short lx = f2bf(x - bf2f(hx));
        const unsigned short ly = f2bf(y - bf2f(hy));
        const unsigned short lz = f2bf(z - bf2f(hz));
        union { unsigned short u[8]; s8v v; } F;
        if (half == 0) {
            F.u[0] = hx; F.u[1] = hy; F.u[2] = hz;
            F.u[3] = hx; F.u[4] = hy; F.u[5] = hz;
            F.u[6] = lx; F.u[7] = ly;
        } else {
            F.u[0] = lz; F.u[1] = lx; F.u[2] = ly; F.u[3] = lz;
            F.u[4] = 0x3F80; F.u[5] = 0x3F80; F.u[6] = 0; F.u[7] = 0;
        }
        bfrag[q] = F.v;
    }

    // chunk's A-data: 32 tiles x 1KB, linear in afmt
    const size_t cbase = ((size_t)dir * NB + b) * NPTS;
    const int4* gsrc = (const int4*)(afmt + cbase * 16) + (size_t)chunk * 2048;

    f16v zf = {};
    float mn[4] = {1e30f, 1e30f, 1e30f, 1e30f};

    // prologue: stage-0 data into regs
    int4 g0 = gsrc[tid];
    int4 g1 = gsrc[256 + tid];

    for (int s = 0; s < 4; ++s) {           // 4 stages x 8 tiles
        const int cur = s & 1;
        __syncthreads();                    // buf[cur] free (stage s-2 consumed)
        sbuf[cur][tid]       = g0;
        sbuf[cur][256 + tid] = g1;
        if (s < 3) {                        // issue next stage's loads EARLY
            g0 = gsrc[(s + 1) * 512 + tid];
            g1 = gsrc[(s + 1) * 512 + 256 + tid];
        }
        __syncthreads();                    // buf[cur] ready

        s8v Ac = i2s(sbuf[cur][l31 * 2 + half]);
#pragma unroll
        for (int t = 0; t < 8; ++t) {
            s8v An;
            if (t < 7) An = i2s(sbuf[cur][(t + 1) * 64 + l31 * 2 + half]);
            f16v c0 = __builtin_amdgcn_mfma_f32_32x32x16_bf16(Ac, bfrag[0], zf, 0,0,0);
            f16v c1 = __builtin_amdgcn_mfma_f32_32x32x16_bf16(Ac, bfrag[1], zf, 0,0,0);
            f16v c2 = __builtin_amdgcn_mfma_f32_32x32x16_bf16(Ac, bfrag[2], zf, 0,0,0);
            f16v c3 = __builtin_amdgcn_mfma_f32_32x32x16_bf16(Ac, bfrag[3], zf, 0,0,0);
            mn[0] = mintree(c0, mn[0]);
            mn[1] = mintree(c1, mn[1]);
            mn[2] = mintree(c2, mn[2]);
            mn[3] = mintree(c3, mn[3]);
            Ac = An;
        }
    }

    // merge row-halves: lane^32 holds the other 16 target-rows
#pragma unroll
    for (int q = 0; q < 4; ++q) mn[q] = fminf(mn[q], __shfl_xor(mn[q], 32));

    if (half == 0) {
        float* dst = pmins + ((size_t)dirb * CHUNKS + chunk) * NPTS + base + l31;
        dst[0]  = mn[0];
        dst[32] = mn[1];
        dst[64] = mn[2];
        dst[96] = mn[3];
    }
}

// ---- K3: merge chunks + |p|^2 + block partial sums + last-block final reduce ----
__global__ __launch_bounds__(256) void chamfer_mergefin(
    const float* __restrict__ pred, const float* __restrict__ target,
    const float* __restrict__ pmins, float* __restrict__ partials,
    int* __restrict__ done, float* __restrict__ out)
{
    const int tid = threadIdx.x;
    const int t = blockIdx.x * 256 + tid;           // 0..65535
    const int dirb = t >> 13;
    const int pr   = t & 8191;
    const int dir  = dirb >> 2;
    const int b    = dirb & 3;

    const float* mrow = pmins + (size_t)dirb * CHUNKS * NPTS + pr;
    float m = fminf(fminf(mrow[0*NPTS], mrow[1*NPTS]), mrow[2*NPTS]);
    m = fminf(fminf(m, mrow[3*NPTS]), mrow[4*NPTS]);
    m = fminf(fminf(m, mrow[5*NPTS]), mrow[6*NPTS]);
    m = fminf(m, mrow[7*NPTS]);

    const float* sp = ((dir == 0) ? pred : target) + ((size_t)b * NPTS + pr) * 3;
    const float p2 = sp[0]*sp[0] + sp[1]*sp[1] + sp[2]*sp[2];
    float v = (m + p2) * (1.0f / 32768.0f);

    __shared__ float s[256];
    __shared__ int lastFlag;
    s[tid] = v;
    __syncthreads();
    for (int wd = 128; wd > 0; wd >>= 1) {
        if (tid < wd) s[tid] += s[tid + wd];
        __syncthreads();
    }
    if (tid == 0) {
        __hip_atomic_store(&partials[blockIdx.x], s[0],
                           __ATOMIC_RELEASE, __HIP_MEMORY_SCOPE_AGENT);
        int prev = __hip_atomic_fetch_add(done, 1,
                           __ATOMIC_ACQ_REL, __HIP_MEMORY_SCOPE_AGENT);
        lastFlag = (prev == gridDim.x - 1);
    }
    __syncthreads();

    if (lastFlag) {   // exactly one block; fixed-order sum -> deterministic
        float acc = __hip_atomic_load(&partials[tid],
                           __ATOMIC_ACQUIRE, __HIP_MEMORY_SCOPE_AGENT);
        s[tid] = acc;
        __syncthreads();
        for (int wd = 128; wd > 0; wd >>= 1) {
            if (tid < wd) s[tid] += s[tid + wd];
            __syncthreads();
        }
        if (tid == 0) out[0] = s[0];
    }
}

extern "C" void kernel_launch(void* const* d_in, const int* in_sizes, int n_in,
                              void* d_out, int out_size, void* d_ws, size_t ws_size,
                              hipStream_t stream)
{
    const float* pred   = (const float*)d_in[0];
    const float* target = (const float*)d_in[1];
    float* out = (float*)d_out;

    // ws: afmt 2 MB | pmins 2 MB | partials 1 KB | done counter
    unsigned short* afmt = (unsigned short*)d_ws;
    float* pmins    = (float*)((char*)d_ws + (size_t)2 * 1024 * 1024);
    float* partials = (float*)((char*)d_ws + (size_t)4 * 1024 * 1024);
    int*   done     = (int*)((char*)d_ws + (size_t)5 * 1024 * 1024);

    chamfer_prep<<<256, 256, 0, stream>>>(pred, target, afmt, done);

    dim3 grid(16, 8, CHUNKS);   // 1024 blocks x 4 waves (v2 geometry)
    chamfer_mfma<<<grid, 256, 0, stream>>>(pred, target, afmt, pmins);

    chamfer_mergefin<<<256, 256, 0, stream>>>(pred, target, pmins, partials, done, out);
}